// Round 6
// baseline (10943.936 us; speedup 1.0000x reference)
//
#include <hip/hip_runtime.h>
#include <hip/hip_bf16.h>
#include <stdint.h>

// ---------------------------------------------------------------------------
// LowRankLSTM  (SEQ=512, BS=64, IN=1024, HID=1024, RANK=256)
//
//   1. Weights -> bf16, B-operands transposed (contiguous K for MFMA frags).
//   2. Precompute recurrent matrices Wrt[c][k], c = h_out*4+gate (i,f,g,o).
//   3. Precompute input projections xp[t][b][h*4+g] bf16 via 2 GEMMs/gate.
//   4. ONE persistent kernel runs all 512 steps: weights in registers,
//      K split across 4 waves, LDS reduction, fused cell, and a hand-rolled
//      device-scope grid barrier between steps (release add + relaxed spin
//      + agent acquire fence -- the ROCm grid.sync pattern).
// ---------------------------------------------------------------------------

typedef __attribute__((ext_vector_type(8))) short short8;   // 8 x bf16
typedef __attribute__((ext_vector_type(4))) float f32x4;

#define MFMA16(a, b, c) __builtin_amdgcn_mfma_f32_16x16x32_bf16((a), (b), (c), 0, 0, 0)

__device__ inline unsigned short f2bf(float f) {
  union { float f; unsigned int u; } v; v.f = f;
  unsigned int r = v.u + 0x7fffu + ((v.u >> 16) & 1u);  // RNE
  return (unsigned short)(r >> 16);
}
__device__ inline float bf2f(unsigned short u) {
  union { unsigned int u; float f; } v; v.u = ((unsigned int)u) << 16; return v.f;
}
__device__ inline float sigmoidf_(float x) {
  return 1.f / (1.f + __expf(-x));
}
__device__ inline float tanhf_(float x) {
  float cx = fminf(fmaxf(x, -15.f), 15.f);
  float e = __expf(2.f * cx);
  return (e - 1.f) / (e + 1.f);
}

// --------------------------- small prep kernels ----------------------------

__global__ __launch_bounds__(256) void convert_f32_bf16(
    const float* __restrict__ src, unsigned short* __restrict__ dst, int n) {
  int i = (blockIdx.x * 256 + threadIdx.x) * 4;
  if (i < n) {
    float4 v = *(const float4*)&src[i];
    ushort4 o;
    o.x = f2bf(v.x); o.y = f2bf(v.y); o.z = f2bf(v.z); o.w = f2bf(v.w);
    *(ushort4*)&dst[i] = o;
  }
}

// dst[c][r] = bf16(src[r][c]);  src is R x C row-major
__global__ __launch_bounds__(256) void transpose_f32_bf16(
    const float* __restrict__ src, unsigned short* __restrict__ dst, int R, int C) {
  int idx = blockIdx.x * 256 + threadIdx.x;
  if (idx < R * C) {
    int r = idx / C, c = idx - r * C;
    dst[(size_t)c * R + r] = f2bf(src[idx]);
  }
}

__global__ void zero_u32(unsigned int* p) { *p = 0u; }

// --------------------------- tiled bf16 GEMM -------------------------------
// C[m*ldc + n*cstride + coff] = bf16( A[M x K] @ (BT[N x K])^T )
// M%128==0, N%128==0, K%64==0.  128x128 tile, BK=64, 4 waves (2x2 of 64x64).
// AF32: A operand is f32 row-major, converted to bf16 in registers.

template <bool AF32>
__device__ inline short8 load_a8(const void* A, size_t row, int K, int k) {
  if constexpr (AF32) {
    const float* a = (const float*)A + row * (size_t)K + k;
    float4 f0 = *(const float4*)a;
    float4 f1 = *(const float4*)(a + 4);
    short8 r;
    r[0] = (short)f2bf(f0.x); r[1] = (short)f2bf(f0.y);
    r[2] = (short)f2bf(f0.z); r[3] = (short)f2bf(f0.w);
    r[4] = (short)f2bf(f1.x); r[5] = (short)f2bf(f1.y);
    r[6] = (short)f2bf(f1.z); r[7] = (short)f2bf(f1.w);
    return r;
  } else {
    return *(const short8*)((const unsigned short*)A + row * (size_t)K + k);
  }
}

template <bool AF32>
__global__ __launch_bounds__(256) void gemm_bf16(
    const void* __restrict__ A, const unsigned short* __restrict__ BT,
    unsigned short* __restrict__ C, int M, int N, int K,
    int ldc, int cstride, int coff) {
  __shared__ unsigned short As[128 * 64];
  __shared__ unsigned short Bs[128 * 64];

  const int tid = threadIdx.x;
  const int m0 = blockIdx.y * 128;
  const int n0 = blockIdx.x * 128;
  const int w = tid >> 6, l = tid & 63;
  const int wm = w >> 1, wn = w & 1;
  const int lr = l & 15, lk = (l >> 4) * 8;

  const int srow = tid >> 3;          // 0..31
  const int sseg = (tid & 7) * 8;     // k-offset in elements

  f32x4 acc[4][4] = {};

  short8 av[4], bv[4];
#pragma unroll
  for (int p = 0; p < 4; ++p) {
    av[p] = load_a8<AF32>(A, m0 + p * 32 + srow, K, sseg);
    bv[p] = *(const short8*)(BT + (size_t)(n0 + p * 32 + srow) * K + sseg);
  }

  for (int k0 = 0; k0 < K; k0 += 64) {
    __syncthreads();   // previous tile's compute done
#pragma unroll
    for (int p = 0; p < 4; ++p) {
      *(short8*)&As[(p * 32 + srow) * 64 + sseg] = av[p];
      *(short8*)&Bs[(p * 32 + srow) * 64 + sseg] = bv[p];
    }
    __syncthreads();   // LDS ready
    if (k0 + 64 < K) {
#pragma unroll
      for (int p = 0; p < 4; ++p) {
        av[p] = load_a8<AF32>(A, m0 + p * 32 + srow, K, k0 + 64 + sseg);
        bv[p] = *(const short8*)(BT + (size_t)(n0 + p * 32 + srow) * K + k0 + 64 + sseg);
      }
    }
#pragma unroll
    for (int kk = 0; kk < 2; ++kk) {
      const int ko = kk * 32 + lk;
      short8 a[4], b[4];
#pragma unroll
      for (int i = 0; i < 4; ++i)
        a[i] = *(const short8*)&As[(wm * 64 + i * 16 + lr) * 64 + ko];
#pragma unroll
      for (int j = 0; j < 4; ++j)
        b[j] = *(const short8*)&Bs[(wn * 64 + j * 16 + lr) * 64 + ko];
#pragma unroll
      for (int i = 0; i < 4; ++i)
#pragma unroll
        for (int j = 0; j < 4; ++j)
          acc[i][j] = MFMA16(a[i], b[j], acc[i][j]);
    }
  }

  // epilogue: C/D layout col = lane&15, row = (lane>>4)*4 + reg
#pragma unroll
  for (int i = 0; i < 4; ++i) {
#pragma unroll
    for (int j = 0; j < 4; ++j) {
      const int rb = m0 + wm * 64 + i * 16 + (l >> 4) * 4;
      const int cb = n0 + wn * 64 + j * 16 + lr;
#pragma unroll
      for (int r = 0; r < 4; ++r)
        C[(size_t)(rb + r) * ldc + (size_t)cb * cstride + coff] = f2bf(acc[i][j][r]);
    }
  }
}

// ----------------------- persistent recurrence kernel ----------------------
// grid = 256 WGs x 256 threads (4 waves).  WG b owns 16 gate-columns
// c0 = b*16 (hidden units c0/4 .. c0/4+3).  Wave w handles K-slice
// [w*256, w*256+256); its 8 B-fragments (Wrt) are preloaded into registers
// for the whole sequence.  Partials reduced via LDS; cell state in registers.
// One device-scope barrier per step; h ping-pongs between two buffers.

#define NWG 256

__global__ __launch_bounds__(256) void lstm_persistent(
    const unsigned short* __restrict__ Wrt,   // [4096][1024] bf16
    const unsigned short* __restrict__ xp,    // [512][64][4096] bf16
    unsigned short* __restrict__ hpp,         // 2 x [64][1024] bf16
    const float* __restrict__ bi, const float* __restrict__ bf_,
    const float* __restrict__ bg, const float* __restrict__ bo,
    float* __restrict__ out,                  // [512][64][1024] ++ hT ++ cT
    unsigned int* __restrict__ bar) {
  __shared__ float part[4][64][17];           // +1 pad: conflict-free stores

  const int tid = threadIdx.x;
  const int w = tid >> 6;                     // wave id = K-slice
  const int l = tid & 63;
  const int lr = l & 15;
  const int lk = (l >> 4) * 8;
  const int c0 = blockIdx.x * 16;
  const int kbase = w * 256;

  // Preload this wave's Wrt fragments into registers (stay for all 512 steps)
  short8 bfrag[8];
#pragma unroll
  for (int kk = 0; kk < 8; ++kk)
    bfrag[kk] = *(const short8*)&Wrt[(size_t)(c0 + lr) * 1024 + kbase + kk * 32 + lk];

  // Cell-phase constants: thread owns cell (batch bb, hidden hid)
  const int bb = tid >> 2;
  const int hh = tid & 3;
  const int hid = (c0 >> 2) + hh;
  const float vbi = bi[hid], vbf = bf_[hid], vbg = bg[hid], vbo = bo[hid];

  float c_reg = 0.f;

  for (int t = 0; t < 512; ++t) {
    // prefetch xp for this step (independent of h; hidden under K-loop)
    ushort4 xq = *(const ushort4*)&xp[(size_t)t * 262144 + bb * 4096 + c0 + hh * 4];

    f32x4 acc[4] = {};
    if (t > 0) {
      const unsigned short* hprev = hpp + ((t & 1) ^ 1) * 65536;
#pragma unroll
      for (int kk = 0; kk < 8; ++kk) {
        const int ko = kbase + kk * 32 + lk;
        short8 a0 = *(const short8*)&hprev[(lr) * 1024 + ko];
        short8 a1 = *(const short8*)&hprev[(16 + lr) * 1024 + ko];
        short8 a2 = *(const short8*)&hprev[(32 + lr) * 1024 + ko];
        short8 a3 = *(const short8*)&hprev[(48 + lr) * 1024 + ko];
        acc[0] = MFMA16(a0, bfrag[kk], acc[0]);
        acc[1] = MFMA16(a1, bfrag[kk], acc[1]);
        acc[2] = MFMA16(a2, bfrag[kk], acc[2]);
        acc[3] = MFMA16(a3, bfrag[kk], acc[3]);
      }
    }

    // stage partials: part[w][batchrow][col]  (C/D: col=lane&15, row=(l>>4)*4+r)
#pragma unroll
    for (int i = 0; i < 4; ++i)
#pragma unroll
      for (int r = 0; r < 4; ++r)
        part[w][i * 16 + (l >> 4) * 4 + r][lr] = acc[i][r];
    __syncthreads();

    // fused cell: sum 4 K-partials + xp + bias
    const int cb = hh * 4;
    float s0 = 0.f, s1 = 0.f, s2 = 0.f, s3 = 0.f;
#pragma unroll
    for (int w2 = 0; w2 < 4; ++w2) {
      s0 += part[w2][bb][cb + 0];
      s1 += part[w2][bb][cb + 1];
      s2 += part[w2][bb][cb + 2];
      s3 += part[w2][bb][cb + 3];
    }
    float ig = sigmoidf_(s0 + bf2f(xq.x) + vbi);
    float fg = sigmoidf_(s1 + bf2f(xq.y) + vbf);
    float gg = tanhf_   (s2 + bf2f(xq.z) + vbg);
    float og = sigmoidf_(s3 + bf2f(xq.w) + vbo);

    c_reg = fg * c_reg + ig * gg;
    float hn = og * tanhf_(c_reg);

    out[(size_t)t * 65536 + bb * 1024 + hid] = hn;
    hpp[(t & 1) * 65536 + bb * 1024 + hid] = f2bf(hn);
    if (t == 511) {
      out[33554432 + bb * 1024 + hid] = hn;
      out[33554432 + 65536 + bb * 1024 + hid] = c_reg;
    }

    // ---- device-scope grid barrier (ROCm grid.sync pattern) ----
    __syncthreads();                          // WG stores done (vmcnt drained)
    if (tid == 0) {
      __hip_atomic_fetch_add(bar, 1u, __ATOMIC_RELEASE, __HIP_MEMORY_SCOPE_AGENT);
      const unsigned int target = (unsigned int)(t + 1) * NWG;
      while (__hip_atomic_load(bar, __ATOMIC_RELAXED, __HIP_MEMORY_SCOPE_AGENT) < target)
        __builtin_amdgcn_s_sleep(1);
      __builtin_amdgcn_fence(__ATOMIC_ACQUIRE, "agent");
    }
    __syncthreads();                          // release all threads; also
                                              // guards LDS reuse next step
  }
}

// ------------------------------- launcher ----------------------------------

extern "C" void kernel_launch(void* const* d_in, const int* in_sizes, int n_in,
                              void* d_out, int out_size, void* d_ws, size_t ws_size,
                              hipStream_t stream) {
  const float* x = (const float*)d_in[0];
  // weight order: ii, hi, if_, hf, ig, hg, io, ho  (U then V each)
  const float* WU[8]; const float* WV[8];
  for (int i = 0; i < 8; ++i) {
    WU[i] = (const float*)d_in[1 + 2 * i];
    WV[i] = (const float*)d_in[2 + 2 * i];
  }
  const int IGATE[4] = {0, 2, 4, 6};  // input-side:  ii, if_, ig, io
  const int HGATE[4] = {1, 3, 5, 7};  // hidden-side: hi, hf, hg, ho
  const float* bi = (const float*)d_in[17];
  const float* bf_ = (const float*)d_in[18];
  const float* bg = (const float*)d_in[19];
  const float* bo = (const float*)d_in[20];

  // ---- workspace layout (bytes), total ~288.5 MB ----
  char* ws = (char*)d_ws;
  const size_t OFF_UTI = 0;                         //  2,097,152  4x U_i^T (256x1024)
  const size_t OFF_VTI = OFF_UTI + 2097152;         //  2,097,152  4x V_i^T (1024x256)
  const size_t OFF_UBH = OFF_VTI + 2097152;         //  2,097,152  4x U_h bf16 (1024x256)
  const size_t OFF_VTH = OFF_UBH + 2097152;         //  2,097,152  4x V_h^T (1024x256)
  const size_t OFF_P   = OFF_VTH + 2097152;         // 16,777,216  P (32768x256) bf16
  const size_t OFF_XP  = OFF_P + 16777216;          // 268,435,456 xp (512x64x4096) bf16
  const size_t OFF_WRT = OFF_XP + 268435456;        //  8,388,608  Wrt (4096x1024) bf16
  const size_t OFF_HPP = OFF_WRT + 8388608;         //    262,144  h ping-pong 2x(64x1024) bf16
  const size_t OFF_BAR = OFF_HPP + 262144;          //         64  grid-barrier counter

  unsigned short* uti = (unsigned short*)(ws + OFF_UTI);
  unsigned short* vti = (unsigned short*)(ws + OFF_VTI);
  unsigned short* ubh = (unsigned short*)(ws + OFF_UBH);
  unsigned short* vth = (unsigned short*)(ws + OFF_VTH);
  unsigned short* pbuf = (unsigned short*)(ws + OFF_P);
  unsigned short* xp = (unsigned short*)(ws + OFF_XP);
  unsigned short* wrt = (unsigned short*)(ws + OFF_WRT);
  unsigned short* hpp = (unsigned short*)(ws + OFF_HPP);
  unsigned int* bar = (unsigned int*)(ws + OFF_BAR);
  float* out = (float*)d_out;

  // 0. zero the barrier counter (ws is re-poisoned before every launch)
  zero_u32<<<1, 1, 0, stream>>>(bar);

  // 1. weight conversions / transposes
  for (int g = 0; g < 4; ++g) {
    transpose_f32_bf16<<<1024, 256, 0, stream>>>(WU[IGATE[g]], uti + g * 262144, 1024, 256);
    transpose_f32_bf16<<<1024, 256, 0, stream>>>(WV[IGATE[g]], vti + g * 262144, 256, 1024);
    convert_f32_bf16<<<256, 256, 0, stream>>>(WU[HGATE[g]], ubh + g * 262144, 262144);
    transpose_f32_bf16<<<1024, 256, 0, stream>>>(WV[HGATE[g]], vth + g * 262144, 256, 1024);
  }

  // 2. Wrt[(h*4+g)*1024 + k] = (U_h @ V_h)[k][h] :  V_h^T @ U_h^T, BT = U_h
  for (int g = 0; g < 4; ++g) {
    gemm_bf16<false><<<dim3(8, 8), 256, 0, stream>>>(
        vth + g * 262144, ubh + g * 262144, wrt,
        1024, 1024, 256, 4096, 1, g * 1024);
  }

  // 3. input projections: P = x @ U_i ; xp[.,h*4+g] = P @ V_i
  for (int g = 0; g < 4; ++g) {
    gemm_bf16<true><<<dim3(2, 256), 256, 0, stream>>>(
        x, uti + g * 262144, pbuf, 32768, 256, 1024, 256, 1, 0);
    gemm_bf16<false><<<dim3(8, 256), 256, 0, stream>>>(
        pbuf, vti + g * 262144, xp, 32768, 1024, 256, 4096, 4, g);
  }

  // 4. recurrence: one persistent kernel, all 512 steps
  lstm_persistent<<<NWG, 256, 0, stream>>>(
      wrt, xp, hpp, bi, bf_, bg, bo, out, bar);
}